// Round 1
// baseline (82.222 us; speedup 1.0000x reference)
//
#include <hip/hip_runtime.h>

// Problem constants from setup_inputs(): B=8, N=20, K=5, Q=15, D=1024.
// B is derived from in_sizes[0]; N/K/Q/D are fixed by the reference setup.
#define DCONST 1024
#define KSUP 5
#define NPROTO 20
#define QPER 15
#define SLOTS (KSUP + QPER)   // 20

// ---------------- Kernel 1: proto mean + term_p ----------------
// grid = B*N blocks, 256 threads. Thread t owns d = 4*t .. 4*t+3.
__global__ __launch_bounds__(256) void proto_kernel(
    const float* __restrict__ emb,     // (B, N, K+Q, D)
    const float* __restrict__ weight,  // (4, D) flattened
    float* __restrict__ proto,         // ws: (B*N, D)
    float* __restrict__ term_p)        // ws: (B*N)
{
    const int bn  = blockIdx.x;          // b*N + n
    const int tid = threadIdx.x;
    const int d0  = tid * 4;

    const float* base = emb + ((size_t)bn * SLOTS) * DCONST + d0;
    float4 s = make_float4(0.f, 0.f, 0.f, 0.f);
#pragma unroll
    for (int k = 0; k < KSUP; ++k) {
        float4 v = *reinterpret_cast<const float4*>(base + (size_t)k * DCONST);
        s.x += v.x; s.y += v.y; s.z += v.z; s.w += v.w;
    }
    const float inv = 1.0f / (float)KSUP;
    s.x *= inv; s.y *= inv; s.z *= inv; s.w *= inv;
    *reinterpret_cast<float4*>(proto + (size_t)bn * DCONST + d0) = s;

    // partial dot(proto, w0)
    float4 w0 = *reinterpret_cast<const float4*>(weight + d0);
    float part = s.x * w0.x + s.y * w0.y + s.z * w0.z + s.w * w0.w;

    // wave reduce (64 lanes)
    for (int off = 32; off; off >>= 1) part += __shfl_down(part, off, 64);
    __shared__ float red[4];
    const int wid = tid >> 6;
    if ((tid & 63) == 0) red[wid] = part;
    __syncthreads();
    if (tid == 0) term_p[bn] = red[0] + red[1] + red[2] + red[3];
}

// ---------------- Kernel 2: fused logits ----------------
// grid = B * (N*Q/4) blocks, 256 threads = 4 waves; each wave owns one
// query row q' in [0, N*Q). Lane l owns d = j*256 + l*4 + {0..3}, j=0..3
// (fully coalesced: one float4 per lane per j => 1 KiB per instruction).
__global__ __launch_bounds__(256) void logits_kernel(
    const float* __restrict__ emb,     // (B, N, K+Q, D)
    const float* __restrict__ weight,  // (4, D)
    const float* __restrict__ bias,    // (1,)
    const float* __restrict__ proto,   // ws: (B*N, D)
    const float* __restrict__ term_p,  // ws: (B*N)
    float* __restrict__ out,           // (B, N*Q, NPROTO)
    int B)
{
    const int tid  = threadIdx.x;
    const int lane = tid & 63;
    const int wid  = tid >> 6;
    const int NQ   = NPROTO * QPER;            // 300
    const int blocks_per_b = NQ / 4;           // 75
    const int b  = blockIdx.x / blocks_per_b;
    const int qp = (blockIdx.x % blocks_per_b) * 4 + wid;   // 0..299
    const int nsrc = qp / QPER;
    const int qq   = qp % QPER;

    const float* qrow =
        emb + (((size_t)(b * NPROTO + nsrc) * SLOTS) + KSUP + qq) * DCONST;

    float4 q4[4], w2r[4], qw3[4];
#pragma unroll
    for (int j = 0; j < 4; ++j) {
        const int d = j * 256 + lane * 4;
        q4[j]  = *reinterpret_cast<const float4*>(qrow + d);
        w2r[j] = *reinterpret_cast<const float4*>(weight + 2 * DCONST + d);
        float4 w3 = *reinterpret_cast<const float4*>(weight + 3 * DCONST + d);
        qw3[j] = make_float4(q4[j].x * w3.x, q4[j].y * w3.y,
                             q4[j].z * w3.z, q4[j].w * w3.w);
    }

    // term_q = dot(q, w1), wave-reduced then broadcast
    float tq = 0.f;
#pragma unroll
    for (int j = 0; j < 4; ++j) {
        const int d = j * 256 + lane * 4;
        float4 w1 = *reinterpret_cast<const float4*>(weight + DCONST + d);
        tq += q4[j].x * w1.x + q4[j].y * w1.y + q4[j].z * w1.z + q4[j].w * w1.w;
    }
    for (int off = 32; off; off >>= 1) tq += __shfl_down(tq, off, 64);
    tq = __shfl(tq, 0, 64);
    const float cbase = tq + bias[0];

    float* orow = out + ((size_t)b * NQ + qp) * NPROTO;
    const float* pbase  = proto + (size_t)b * NPROTO * DCONST;
    const float* tpbase = term_p + b * NPROTO;

    for (int n = 0; n < NPROTO; ++n) {
        float acc = 0.f;
#pragma unroll
        for (int j = 0; j < 4; ++j) {
            const int d = j * 256 + lane * 4;
            float4 p = *reinterpret_cast<const float4*>(pbase + (size_t)n * DCONST + d);
            acc += fabsf(p.x - q4[j].x) * w2r[j].x + qw3[j].x * p.x;
            acc += fabsf(p.y - q4[j].y) * w2r[j].y + qw3[j].y * p.y;
            acc += fabsf(p.z - q4[j].z) * w2r[j].z + qw3[j].z * p.z;
            acc += fabsf(p.w - q4[j].w) * w2r[j].w + qw3[j].w * p.w;
        }
        for (int off = 32; off; off >>= 1) acc += __shfl_down(acc, off, 64);
        if (lane == 0) orow[n] = acc + cbase + tpbase[n];
    }
}

extern "C" void kernel_launch(void* const* d_in, const int* in_sizes, int n_in,
                              void* d_out, int out_size, void* d_ws, size_t ws_size,
                              hipStream_t stream) {
    const float* emb    = (const float*)d_in[0];
    const float* weight = (const float*)d_in[1];
    const float* bias   = (const float*)d_in[2];
    float* out = (float*)d_out;

    const int B = in_sizes[0] / (NPROTO * SLOTS * DCONST);   // 8

    float* proto  = (float*)d_ws;                              // B*N*D floats
    float* term_p = proto + (size_t)B * NPROTO * DCONST;       // B*N floats

    proto_kernel<<<B * NPROTO, 256, 0, stream>>>(emb, weight, proto, term_p);

    const int NQ = NPROTO * QPER;  // 300
    logits_kernel<<<B * (NQ / 4), 256, 0, stream>>>(emb, weight, bias,
                                                    proto, term_p, out, B);
}